// Round 4
// baseline (654.765 us; speedup 1.0000x reference)
//
#include <hip/hip_runtime.h>
#include <math.h>
#include <stddef.h>

#define HQ   16
#define HKV  8
#define DH   128
#define HID  2048
#define CC   16384
#define SPAD 16896          // padded score row length (>= CC+1)
#define AVCH 17             // k_av chunks of 1024: 17*1024 >= 16385

// d_out layout (FLOAT32, 4096 elements): [attn 2048][k_new 8*128][v 8*128]

// ---- K1: QKV projections (fp32 in). One wave per output element.
// raw[0..2047]=q (16 heads x 128), [2048..3071]=k (8x128), [3072..4095]=v (8x128)
__global__ void k_qkv(const float* __restrict__ x,
                      const float* __restrict__ Wq,
                      const float* __restrict__ Wk,
                      const float* __restrict__ Wv,
                      float* __restrict__ raw){
  int wave = threadIdx.x >> 6, lane = threadIdx.x & 63;
  int e = blockIdx.x * 4 + wave;
  const float* W;
  if (e < 2048)      W = Wq + (size_t)e * HID;
  else if (e < 3072) W = Wk + (size_t)(e - 2048) * HID;
  else               W = Wv + (size_t)(e - 3072) * HID;
  float acc = 0.f;
  #pragma unroll
  for (int j = 0; j < 4; ++j){
    int base = (j * 64 + lane) * 8;
    float4 a0 = *(const float4*)(x + base);
    float4 a1 = *(const float4*)(x + base + 4);
    float4 b0 = *(const float4*)(W + base);
    float4 b1 = *(const float4*)(W + base + 4);
    acc += a0.x*b0.x + a0.y*b0.y + a0.z*b0.z + a0.w*b0.w
         + a1.x*b1.x + a1.y*b1.y + a1.z*b1.z + a1.w*b1.w;
  }
  #pragma unroll
  for (int off = 32; off; off >>= 1) acc += __shfl_down(acc, off, 64);
  if (lane == 0) raw[e] = acc;
}

// ---- K2: RMSNorm + RoPE (q,k), v passthrough. out is FLOAT32.
__global__ void k_normrope(const float* __restrict__ raw,
                           const float* __restrict__ cosb,
                           const float* __restrict__ sinb,
                           const float* __restrict__ qw,
                           const float* __restrict__ kw,
                           float* __restrict__ qf,
                           float* __restrict__ kf,
                           float* __restrict__ out){
  __shared__ float lds[DH];
  __shared__ float wsum[2];
  int b = blockIdx.x, t = threadIdx.x;
  if (b >= 24){  // v copy to d_out
    int h = b - 24;
    out[3072 + h * DH + t] = raw[3072 + h * DH + t];
    return;
  }
  bool isq = (b < 16);
  int h = isq ? b : b - 16;
  float val = isq ? raw[h * DH + t] : raw[2048 + h * DH + t];
  float ss = val * val;
  #pragma unroll
  for (int off = 32; off; off >>= 1) ss += __shfl_down(ss, off, 64);
  if ((t & 63) == 0) wsum[t >> 6] = ss;
  __syncthreads();
  float rms = sqrtf((wsum[0] + wsum[1]) / 128.f + 1e-6f);
  float w = isq ? qw[t] : kw[t];
  float normed = val / rms * w;
  lds[t] = normed;
  __syncthreads();
  float rot = (t < 64) ? -lds[t + 64] : lds[t - 64];
  float res = normed * cosb[t] + rot * sinb[t];
  if (isq) qf[h * DH + t] = res;
  else { kf[h * DH + t] = res; out[2048 + h * DH + t] = res; }
}

// ---- K3: scores. grid = HQ * 65 blocks, 256 threads; thread -> one position c.
__global__ void k_scores(const float* __restrict__ qf,
                         const float* __restrict__ kf,
                         const float* __restrict__ kcache,  // [HKV][DH][CC]
                         const float* __restrict__ mask,    // [CC+1]
                         float* __restrict__ S){            // [HQ][SPAD]
  __shared__ float q_s[DH];
  int qh = blockIdx.x / 65, cb = blockIdx.x % 65;
  int kv = qh >> 1;
  int t = threadIdx.x;
  if (t < DH) q_s[t] = qf[qh * DH + t];
  __syncthreads();
  int c = cb * 256 + t;
  if (c > CC) return;
  const float scale = 0.08838834764831845f;  // 128^-0.5
  float acc = 0.f;
  if (c < CC){
    const float* kp = kcache + (size_t)kv * DH * CC + c;
    #pragma unroll 8
    for (int d = 0; d < DH; ++d) acc += q_s[d] * kp[(size_t)d * CC];
  } else {
    const float* kp = kf + kv * DH;
    #pragma unroll 8
    for (int d = 0; d < DH; ++d) acc += q_s[d] * kp[d];
  }
  S[(size_t)qh * SPAD + c] = acc * scale + mask[c];
}

// ---- K4: softmax over S[qh][0..CC] in place. 16 blocks x 256 threads.
__global__ void k_softmax(float* __restrict__ S){
  __shared__ float red[4];
  __shared__ float mm, ll;
  int qh = blockIdx.x, t = threadIdx.x;
  float* row = S + (size_t)qh * SPAD;
  int wv = t >> 6, ln = t & 63;
  // pass 1: max
  float m = -1e30f;
  for (int c = t; c <= CC; c += 256) m = fmaxf(m, row[c]);
  #pragma unroll
  for (int off = 32; off; off >>= 1) m = fmaxf(m, __shfl_down(m, off, 64));
  if (ln == 0) red[wv] = m;
  __syncthreads();
  if (t == 0) mm = fmaxf(fmaxf(red[0], red[1]), fmaxf(red[2], red[3]));
  __syncthreads();
  float M = mm;
  // pass 2: sum of exp
  float s = 0.f;
  for (int c = t; c <= CC; c += 256) s += __expf(row[c] - M);
  #pragma unroll
  for (int off = 32; off; off >>= 1) s += __shfl_down(s, off, 64);
  __syncthreads();
  if (ln == 0) red[wv] = s;
  __syncthreads();
  if (t == 0) ll = red[0] + red[1] + red[2] + red[3];
  __syncthreads();
  float L = ll;
  // pass 3: write probs
  for (int c = t; c <= CC; c += 256) row[c] = __expf(row[c] - M) / L;
}

// ---- K5: partial O = sum_c p[c]*V[c][:]. grid = HQ*AVCH blocks, 128 threads (thread=d).
__global__ void k_av(const float* __restrict__ S,        // probs [HQ][SPAD]
                     const float* __restrict__ vcache,   // [HKV][CC][DH]
                     const float* __restrict__ vnew,     // raw+3072: [HKV][DH]
                     float* __restrict__ opart){         // [HQ][AVCH][DH]
  int qh = blockIdx.x / AVCH, chunk = blockIdx.x % AVCH;
  int kv = qh >> 1;
  int d = threadIdx.x;
  const float* prow = S + (size_t)qh * SPAD;
  float acc = 0.f;
  for (int i = 0; i < 1024; ++i){
    int c = chunk * 1024 + i;
    if (c > CC) break;
    float p = prow[c];
    float v = (c < CC) ? vcache[((size_t)kv * CC + c) * DH + d]
                       : vnew[kv * DH + d];
    acc += p * v;
  }
  opart[((size_t)qh * AVCH + chunk) * DH + d] = acc;
}

// ---- K6: sum partials -> attn_in[qh*DH+d]
__global__ void k_osum(const float* __restrict__ opart, float* __restrict__ attn_in){
  int qh = blockIdx.x, d = threadIdx.x;
  float o = 0.f;
  #pragma unroll
  for (int ch = 0; ch < AVCH; ++ch)
    o += opart[((size_t)qh * AVCH + ch) * DH + d];
  attn_in[qh * DH + d] = o;
}

// ---- K7: o_proj GEMV. One wave per output element. out FLOAT32.
__global__ void k_oproj(const float* __restrict__ attn_in,
                        const float* __restrict__ Wo,
                        float* __restrict__ out){
  int wave = threadIdx.x >> 6, lane = threadIdx.x & 63;
  int e = blockIdx.x * 4 + wave;
  const float* W = Wo + (size_t)e * HID;
  float acc = 0.f;
  #pragma unroll
  for (int j = 0; j < 4; ++j){
    int base = (j * 64 + lane) * 8;
    float4 a0 = *(const float4*)(attn_in + base);
    float4 a1 = *(const float4*)(attn_in + base + 4);
    float4 b0 = *(const float4*)(W + base);
    float4 b1 = *(const float4*)(W + base + 4);
    acc += a0.x*b0.x + a0.y*b0.y + a0.z*b0.z + a0.w*b0.w
         + a1.x*b1.x + a1.y*b1.y + a1.z*b1.z + a1.w*b1.w;
  }
  #pragma unroll
  for (int off = 32; off; off >>= 1) acc += __shfl_down(acc, off, 64);
  if (lane == 0) out[e] = acc;
}

extern "C" void kernel_launch(void* const* d_in, const int* in_sizes, int n_in,
                              void* d_out, int out_size, void* d_ws, size_t ws_size,
                              hipStream_t stream){
  const float* x    = (const float*)d_in[0];
  const float* cosb = (const float*)d_in[1];
  const float* sinb = (const float*)d_in[2];
  const float* mask = (const float*)d_in[3];
  const float* kc   = (const float*)d_in[4];
  const float* vc   = (const float*)d_in[5];
  const float* Wq   = (const float*)d_in[6];
  const float* Wk   = (const float*)d_in[7];
  const float* Wv   = (const float*)d_in[8];
  const float* Wo   = (const float*)d_in[9];
  const float* qw   = (const float*)d_in[10];
  const float* kw   = (const float*)d_in[11];
  float* out = (float*)d_out;
  float* ws = (float*)d_ws;
  float* raw     = ws;                    // 4096
  float* qf      = ws + 4096;             // 2048
  float* kf      = ws + 6144;             // 1024
  float* S       = ws + 8192;             // HQ*SPAD = 270336
  float* opart   = ws + 8192 + 270336;    // HQ*AVCH*DH = 34816
  float* attn_in = ws + 8192 + 270336 + 34816;  // 2048

  k_qkv    <<<1024, 256, 0, stream>>>(x, Wq, Wk, Wv, raw);
  k_normrope<<<32,  128, 0, stream>>>(raw, cosb, sinb, qw, kw, qf, kf, out);
  k_scores <<<HQ * 65, 256, 0, stream>>>(qf, kf, kc, mask, S);
  k_softmax<<<HQ, 256, 0, stream>>>(S);
  k_av     <<<HQ * AVCH, 128, 0, stream>>>(S, vc, raw + 3072, opart);
  k_osum   <<<HQ, DH, 0, stream>>>(opart, attn_in);
  k_oproj  <<<512, 256, 0, stream>>>(attn_in, Wo, out);
}

// Round 5
// 240.833 us; speedup vs baseline: 2.7188x; 2.7188x over previous
//
#include <hip/hip_runtime.h>
#include <math.h>
#include <stddef.h>

#define HQ   16
#define HKV  8
#define DH   128
#define HID  2048
#define CC   16384
#define SPAD 16896          // padded score row length (>= CC+1)
#define NSCH 33             // score chunks of 512: 33*512 = 16896 >= 16385
#define NAV  65             // AV chunks of 256:   65*256 = 16640 >= 16385

// d_out layout (FLOAT32, 4096 elements): [attn 2048][k_new 8*128][v 8*128]

// ---- K1: QKV projections. One wave per output element.
// raw[0..2047]=q (16x128), [2048..3071]=k (8x128), [3072..4095]=v (8x128)
__global__ void k_qkv(const float* __restrict__ x,
                      const float* __restrict__ Wq,
                      const float* __restrict__ Wk,
                      const float* __restrict__ Wv,
                      float* __restrict__ raw){
  int wave = threadIdx.x >> 6, lane = threadIdx.x & 63;
  int e = blockIdx.x * 4 + wave;
  const float* W;
  if (e < 2048)      W = Wq + (size_t)e * HID;
  else if (e < 3072) W = Wk + (size_t)(e - 2048) * HID;
  else               W = Wv + (size_t)(e - 3072) * HID;
  float acc = 0.f;
  #pragma unroll
  for (int j = 0; j < 4; ++j){
    int base = (j * 64 + lane) * 8;
    float4 a0 = *(const float4*)(x + base);
    float4 a1 = *(const float4*)(x + base + 4);
    float4 b0 = *(const float4*)(W + base);
    float4 b1 = *(const float4*)(W + base + 4);
    acc += a0.x*b0.x + a0.y*b0.y + a0.z*b0.z + a0.w*b0.w
         + a1.x*b1.x + a1.y*b1.y + a1.z*b1.z + a1.w*b1.w;
  }
  #pragma unroll
  for (int off = 32; off; off >>= 1) acc += __shfl_down(acc, off, 64);
  if (lane == 0) raw[e] = acc;
}

// ---- K2: RMSNorm + RoPE (q,k), v passthrough.
__global__ void k_normrope(const float* __restrict__ raw,
                           const float* __restrict__ cosb,
                           const float* __restrict__ sinb,
                           const float* __restrict__ qw,
                           const float* __restrict__ kw,
                           float* __restrict__ qf,
                           float* __restrict__ kf,
                           float* __restrict__ out){
  __shared__ float lds[DH];
  __shared__ float wsum[2];
  int b = blockIdx.x, t = threadIdx.x;
  if (b >= 24){  // v copy to d_out
    int h = b - 24;
    out[3072 + h * DH + t] = raw[3072 + h * DH + t];
    return;
  }
  bool isq = (b < 16);
  int h = isq ? b : b - 16;
  float val = isq ? raw[h * DH + t] : raw[2048 + h * DH + t];
  float ss = val * val;
  #pragma unroll
  for (int off = 32; off; off >>= 1) ss += __shfl_down(ss, off, 64);
  if ((t & 63) == 0) wsum[t >> 6] = ss;
  __syncthreads();
  float rms = sqrtf((wsum[0] + wsum[1]) / 128.f + 1e-6f);
  float w = isq ? qw[t] : kw[t];
  float normed = val / rms * w;
  lds[t] = normed;
  __syncthreads();
  float rot = (t < 64) ? -lds[t + 64] : lds[t - 64];
  float res = normed * cosb[t] + rot * sinb[t];
  if (isq) qf[h * DH + t] = res;
  else { kf[h * DH + t] = res; out[2048 + h * DH + t] = res; }
}

// ---- K3: scores for BOTH GQA heads + per-chunk softmax partials.
// grid = HKV * NSCH, 256 threads; thread -> 2 adjacent positions.
__global__ void k_scores(const float* __restrict__ qf,
                         const float* __restrict__ kf,
                         const float* __restrict__ kcache,  // [HKV][DH][CC]
                         const float* __restrict__ mask,    // [CC+1]
                         float* __restrict__ S,             // [HQ][SPAD] raw scores
                         float* __restrict__ spart){        // [HQ][NSCH][2] = {m,l}
  __shared__ float q_s[2][DH];
  __shared__ float red[8];
  int kv = blockIdx.x / NSCH, ch = blockIdx.x % NSCH;
  int c0 = ch * 512;
  int t = threadIdx.x;
  q_s[t >> 7][t & 127] = qf[(kv * 2 + (t >> 7)) * DH + (t & 127)];
  __syncthreads();
  const float scale = 0.08838834764831845f;  // 128^-0.5

  float sc[2][2];
  int cA = c0 + 2 * t;
  {
    float d0a = 0.f, d0b = 0.f, d1a = 0.f, d1b = 0.f;
    if (cA < CC){
      const float* kp = kcache + (size_t)kv * DH * CC + cA;
      #pragma unroll 8
      for (int d = 0; d < DH; ++d){
        float2 kk = *(const float2*)(kp + (size_t)d * CC);
        float q0 = q_s[0][d], q1 = q_s[1][d];
        d0a += q0 * kk.x; d0b += q0 * kk.y;
        d1a += q1 * kk.x; d1b += q1 * kk.y;
      }
      float mA = mask[cA], mB = mask[cA + 1];
      sc[0][0] = d0a * scale + mA; sc[0][1] = d0b * scale + mB;
      sc[1][0] = d1a * scale + mA; sc[1][1] = d1b * scale + mB;
      *(float2*)(S + (size_t)(kv * 2)     * SPAD + cA) = make_float2(sc[0][0], sc[0][1]);
      *(float2*)(S + (size_t)(kv * 2 + 1) * SPAD + cA) = make_float2(sc[1][0], sc[1][1]);
    } else if (cA == CC){
      const float* kp = kf + kv * DH;
      #pragma unroll 8
      for (int d = 0; d < DH; ++d){
        float kd = kp[d];
        d0a += q_s[0][d] * kd; d1a += q_s[1][d] * kd;
      }
      float mA = mask[cA];
      sc[0][0] = d0a * scale + mA; sc[1][0] = d1a * scale + mA;
      sc[0][1] = -1e30f; sc[1][1] = -1e30f;
      S[(size_t)(kv * 2)     * SPAD + cA] = sc[0][0];
      S[(size_t)(kv * 2 + 1) * SPAD + cA] = sc[1][0];
    } else {
      sc[0][0] = sc[0][1] = sc[1][0] = sc[1][1] = -1e30f;
    }
  }

  // per-chunk softmax partials (max + expsum) per head
  int wv = t >> 6, ln = t & 63;
  float lmax0 = fmaxf(sc[0][0], sc[0][1]);
  float lmax1 = fmaxf(sc[1][0], sc[1][1]);
  #pragma unroll
  for (int off = 32; off; off >>= 1){
    lmax0 = fmaxf(lmax0, __shfl_down(lmax0, off, 64));
    lmax1 = fmaxf(lmax1, __shfl_down(lmax1, off, 64));
  }
  if (ln == 0){ red[wv] = lmax0; red[4 + wv] = lmax1; }
  __syncthreads();
  float m0 = fmaxf(fmaxf(red[0], red[1]), fmaxf(red[2], red[3]));
  float m1 = fmaxf(fmaxf(red[4], red[5]), fmaxf(red[6], red[7]));
  float ls0 = __expf(sc[0][0] - m0) + __expf(sc[0][1] - m0);
  float ls1 = __expf(sc[1][0] - m1) + __expf(sc[1][1] - m1);
  #pragma unroll
  for (int off = 32; off; off >>= 1){
    ls0 += __shfl_down(ls0, off, 64);
    ls1 += __shfl_down(ls1, off, 64);
  }
  __syncthreads();
  if (ln == 0){ red[wv] = ls0; red[4 + wv] = ls1; }
  __syncthreads();
  if (t == 0){
    float l0 = red[0] + red[1] + red[2] + red[3];
    float l1 = red[4] + red[5] + red[6] + red[7];
    spart[((size_t)(kv * 2)     * NSCH + ch) * 2]     = m0;
    spart[((size_t)(kv * 2)     * NSCH + ch) * 2 + 1] = l0;
    spart[((size_t)(kv * 2 + 1) * NSCH + ch) * 2]     = m1;
    spart[((size_t)(kv * 2 + 1) * NSCH + ch) * 2 + 1] = l1;
  }
}

// ---- K4: reduce chunk partials -> global (M, L) per q-head. grid=HQ, 64 threads.
__global__ void k_red(const float* __restrict__ spart, float2* __restrict__ ML){
  int qh = blockIdx.x, lane = threadIdx.x;
  float m = -1e30f, l = 0.f;
  if (lane < NSCH){
    m = spart[((size_t)qh * NSCH + lane) * 2];
    l = spart[((size_t)qh * NSCH + lane) * 2 + 1];
  }
  float M = m;
  #pragma unroll
  for (int off = 32; off; off >>= 1) M = fmaxf(M, __shfl_down(M, off, 64));
  M = __shfl(M, 0, 64);
  float term = l * __expf(m - M);
  #pragma unroll
  for (int off = 32; off; off >>= 1) term += __shfl_down(term, off, 64);
  if (lane == 0) ML[qh] = make_float2(M, term);
}

// ---- K5: partial O for BOTH GQA heads. grid = HKV*NAV, 256 threads.
// 8 position-slices x 32 dim-threads (float4). p = exp(S-M)/L on the fly.
__global__ void k_av(const float* __restrict__ S,
                     const float2* __restrict__ ML,
                     const float* __restrict__ vcache,   // [HKV][CC][DH]
                     const float* __restrict__ vnew,     // raw+3072: [HKV][DH]
                     float* __restrict__ opart){         // [HQ][NAV][DH]
  __shared__ float part[2][8][DH];
  int kv = blockIdx.x / NAV, ch = blockIdx.x % NAV;
  int c0 = ch * 256;
  int t = threadIdx.x;
  int s = t >> 5, d4 = (t & 31) * 4;
  float2 ml0 = ML[kv * 2], ml1 = ML[kv * 2 + 1];
  float M0 = ml0.x, Li0 = 1.f / ml0.y;
  float M1 = ml1.x, Li1 = 1.f / ml1.y;
  const float* S0 = S + (size_t)(kv * 2)     * SPAD;
  const float* S1 = S + (size_t)(kv * 2 + 1) * SPAD;
  float4 a0 = make_float4(0.f, 0.f, 0.f, 0.f);
  float4 a1 = make_float4(0.f, 0.f, 0.f, 0.f);
  for (int i = 0; i < 32; ++i){
    int c = c0 + i * 8 + s;
    if (c > CC) break;
    float p0 = __expf(S0[c] - M0);
    float p1 = __expf(S1[c] - M1);
    float4 v = (c < CC) ? *(const float4*)(vcache + ((size_t)kv * CC + c) * DH + d4)
                        : *(const float4*)(vnew + kv * DH + d4);
    a0.x += p0 * v.x; a0.y += p0 * v.y; a0.z += p0 * v.z; a0.w += p0 * v.w;
    a1.x += p1 * v.x; a1.y += p1 * v.y; a1.z += p1 * v.z; a1.w += p1 * v.w;
  }
  *(float4*)&part[0][s][d4] = a0;
  *(float4*)&part[1][s][d4] = a1;
  __syncthreads();
  {
    int hh = t >> 7, d = t & 127;
    float o = 0.f;
    #pragma unroll
    for (int ss = 0; ss < 8; ++ss) o += part[hh][ss][d];
    float Li = hh ? Li1 : Li0;
    int qh = kv * 2 + hh;
    opart[((size_t)qh * NAV + ch) * DH + d] = o * Li;
  }
}

// ---- K6: sum partials -> attn_in[qh*DH+d]
__global__ void k_osum(const float* __restrict__ opart, float* __restrict__ attn_in){
  int qh = blockIdx.x, d = threadIdx.x;
  float o = 0.f;
  for (int ch = 0; ch < NAV; ++ch)
    o += opart[((size_t)qh * NAV + ch) * DH + d];
  attn_in[qh * DH + d] = o;
}

// ---- K7: o_proj GEMV. One wave per output element.
__global__ void k_oproj(const float* __restrict__ attn_in,
                        const float* __restrict__ Wo,
                        float* __restrict__ out){
  int wave = threadIdx.x >> 6, lane = threadIdx.x & 63;
  int e = blockIdx.x * 4 + wave;
  const float* W = Wo + (size_t)e * HID;
  float acc = 0.f;
  #pragma unroll
  for (int j = 0; j < 4; ++j){
    int base = (j * 64 + lane) * 8;
    float4 a0 = *(const float4*)(attn_in + base);
    float4 a1 = *(const float4*)(attn_in + base + 4);
    float4 b0 = *(const float4*)(W + base);
    float4 b1 = *(const float4*)(W + base + 4);
    acc += a0.x*b0.x + a0.y*b0.y + a0.z*b0.z + a0.w*b0.w
         + a1.x*b1.x + a1.y*b1.y + a1.z*b1.z + a1.w*b1.w;
  }
  #pragma unroll
  for (int off = 32; off; off >>= 1) acc += __shfl_down(acc, off, 64);
  if (lane == 0) out[e] = acc;
}

extern "C" void kernel_launch(void* const* d_in, const int* in_sizes, int n_in,
                              void* d_out, int out_size, void* d_ws, size_t ws_size,
                              hipStream_t stream){
  const float* x    = (const float*)d_in[0];
  const float* cosb = (const float*)d_in[1];
  const float* sinb = (const float*)d_in[2];
  const float* mask = (const float*)d_in[3];
  const float* kc   = (const float*)d_in[4];
  const float* vc   = (const float*)d_in[5];
  const float* Wq   = (const float*)d_in[6];
  const float* Wk   = (const float*)d_in[7];
  const float* Wv   = (const float*)d_in[8];
  const float* Wo   = (const float*)d_in[9];
  const float* qw   = (const float*)d_in[10];
  const float* kw   = (const float*)d_in[11];
  float* out = (float*)d_out;
  float* ws = (float*)d_ws;
  float* raw     = ws;                          // 4096
  float* qf      = ws + 4096;                   // 2048
  float* kf      = ws + 6144;                   // 1024
  float* S       = ws + 8192;                   // 16*16896 = 270336
  float* spart   = ws + 278528;                 // 16*33*2 = 1056
  float2* ML     = (float2*)(ws + 279584);      // 16*2 = 32 floats (8B aligned)
  float* opart   = ws + 279616;                 // 16*65*128 = 133120
  float* attn_in = ws + 412736;                 // 2048

  k_qkv     <<<1024, 256, 0, stream>>>(x, Wq, Wk, Wv, raw);
  k_normrope<<<32,   128, 0, stream>>>(raw, cosb, sinb, qw, kw, qf, kf, out);
  k_scores  <<<HKV * NSCH, 256, 0, stream>>>(qf, kf, kc, mask, S, spart);
  k_red     <<<HQ, 64, 0, stream>>>(spart, ML);
  k_av      <<<HKV * NAV, 256, 0, stream>>>(S, ML, vc, raw + 3072, opart);
  k_osum    <<<HQ, DH, 0, stream>>>(opart, attn_in);
  k_oproj   <<<512, 256, 0, stream>>>(attn_in, Wo, out);
}

// Round 6
// 217.813 us; speedup vs baseline: 3.0061x; 1.1057x over previous
//
#include <hip/hip_runtime.h>
#include <math.h>
#include <stddef.h>

#define HQ   16
#define HKV  8
#define DH   128
#define HID  2048
#define CC   16384
#define SPAD 16896          // padded score row stride (>= CC+1)
#define NSCH 65             // score chunks of 256: 65*256 = 16640 >= 16385
#define NAV  64             // AV chunks of 256 covering c in [0, CC)

// d_out layout (FLOAT32, 4096 elements): [attn 2048][k_new 8*128][v 8*128]

// ---- K1: QKV projections. One wave per output element.
// raw[0..2047]=q (16x128), [2048..3071]=k (8x128), [3072..4095]=v (8x128)
__global__ void k_qkv(const float* __restrict__ x,
                      const float* __restrict__ Wq,
                      const float* __restrict__ Wk,
                      const float* __restrict__ Wv,
                      float* __restrict__ raw){
  int wave = threadIdx.x >> 6, lane = threadIdx.x & 63;
  int e = blockIdx.x * 4 + wave;
  const float* W;
  if (e < 2048)      W = Wq + (size_t)e * HID;
  else if (e < 3072) W = Wk + (size_t)(e - 2048) * HID;
  else               W = Wv + (size_t)(e - 3072) * HID;
  float acc = 0.f;
  #pragma unroll
  for (int j = 0; j < 4; ++j){
    int base = (j * 64 + lane) * 8;
    float4 a0 = *(const float4*)(x + base);
    float4 a1 = *(const float4*)(x + base + 4);
    float4 b0 = *(const float4*)(W + base);
    float4 b1 = *(const float4*)(W + base + 4);
    acc += a0.x*b0.x + a0.y*b0.y + a0.z*b0.z + a0.w*b0.w
         + a1.x*b1.x + a1.y*b1.y + a1.z*b1.z + a1.w*b1.w;
  }
  #pragma unroll
  for (int off = 32; off; off >>= 1) acc += __shfl_down(acc, off, 64);
  if (lane == 0) raw[e] = acc;
}

// ---- K2: RMSNorm + RoPE (q,k), v passthrough.
__global__ void k_normrope(const float* __restrict__ raw,
                           const float* __restrict__ cosb,
                           const float* __restrict__ sinb,
                           const float* __restrict__ qw,
                           const float* __restrict__ kw,
                           float* __restrict__ qf,
                           float* __restrict__ kf,
                           float* __restrict__ out){
  __shared__ float lds[DH];
  __shared__ float wsum[2];
  int b = blockIdx.x, t = threadIdx.x;
  if (b >= 24){  // v copy to d_out
    int h = b - 24;
    out[3072 + h * DH + t] = raw[3072 + h * DH + t];
    return;
  }
  bool isq = (b < 16);
  int h = isq ? b : b - 16;
  float val = isq ? raw[h * DH + t] : raw[2048 + h * DH + t];
  float ss = val * val;
  #pragma unroll
  for (int off = 32; off; off >>= 1) ss += __shfl_down(ss, off, 64);
  if ((t & 63) == 0) wsum[t >> 6] = ss;
  __syncthreads();
  float rms = sqrtf((wsum[0] + wsum[1]) / 128.f + 1e-6f);
  float w = isq ? qw[t] : kw[t];
  float normed = val / rms * w;
  lds[t] = normed;
  __syncthreads();
  float rot = (t < 64) ? -lds[t + 64] : lds[t - 64];
  float res = normed * cosb[t] + rot * sinb[t];
  if (isq) qf[h * DH + t] = res;
  else { kf[h * DH + t] = res; out[2048 + h * DH + t] = res; }
}

// ---- K3: scores for BOTH GQA heads + per-chunk softmax partials.
// grid = HKV * NSCH, 256 threads; thread -> ONE position. unroll-8 d-loop for ILP.
__global__ void k_scores(const float* __restrict__ qf,
                         const float* __restrict__ kf,
                         const float* __restrict__ kcache,  // [HKV][DH][CC]
                         const float* __restrict__ mask,    // [CC+1]
                         float* __restrict__ S,             // [HQ][SPAD] raw scores
                         float* __restrict__ spart){        // [HQ][NSCH][2] = {m,l}
  __shared__ float q_s[2][DH];
  __shared__ float red[8];
  int kv = blockIdx.x / NSCH, ch = blockIdx.x % NSCH;
  int c0 = ch * 256;
  int t = threadIdx.x;
  q_s[t >> 7][t & 127] = qf[(kv * 2 + (t >> 7)) * DH + (t & 127)];
  __syncthreads();
  const float scale = 0.08838834764831845f;  // 128^-0.5

  int c = c0 + t;
  float s0, s1;
  if (c < CC){
    const float* kp = kcache + (size_t)kv * DH * CC + c;
    float a0 = 0.f, a1 = 0.f;
    #pragma unroll 8
    for (int d = 0; d < DH; ++d){
      float kd = kp[(size_t)d * CC];
      a0 += q_s[0][d] * kd;
      a1 += q_s[1][d] * kd;
    }
    float mk = mask[c];
    s0 = a0 * scale + mk;
    s1 = a1 * scale + mk;
    S[(size_t)(kv * 2)     * SPAD + c] = s0;
    S[(size_t)(kv * 2 + 1) * SPAD + c] = s1;
  } else if (c == CC){
    const float* kp = kf + kv * DH;
    float a0 = 0.f, a1 = 0.f;
    #pragma unroll 8
    for (int d = 0; d < DH; ++d){
      float kd = kp[d];
      a0 += q_s[0][d] * kd;
      a1 += q_s[1][d] * kd;
    }
    float mk = mask[c];
    s0 = a0 * scale + mk;
    s1 = a1 * scale + mk;
    S[(size_t)(kv * 2)     * SPAD + c] = s0;
    S[(size_t)(kv * 2 + 1) * SPAD + c] = s1;
  } else {
    s0 = -1e30f; s1 = -1e30f;
  }

  // per-chunk softmax partials (max + expsum) per head
  int wv = t >> 6, ln = t & 63;
  float lmax0 = s0, lmax1 = s1;
  #pragma unroll
  for (int off = 32; off; off >>= 1){
    lmax0 = fmaxf(lmax0, __shfl_down(lmax0, off, 64));
    lmax1 = fmaxf(lmax1, __shfl_down(lmax1, off, 64));
  }
  if (ln == 0){ red[wv] = lmax0; red[4 + wv] = lmax1; }
  __syncthreads();
  float m0 = fmaxf(fmaxf(red[0], red[1]), fmaxf(red[2], red[3]));
  float m1 = fmaxf(fmaxf(red[4], red[5]), fmaxf(red[6], red[7]));
  float ls0 = __expf(s0 - m0);
  float ls1 = __expf(s1 - m1);
  #pragma unroll
  for (int off = 32; off; off >>= 1){
    ls0 += __shfl_down(ls0, off, 64);
    ls1 += __shfl_down(ls1, off, 64);
  }
  __syncthreads();
  if (ln == 0){ red[wv] = ls0; red[4 + wv] = ls1; }
  __syncthreads();
  if (t == 0){
    float l0 = red[0] + red[1] + red[2] + red[3];
    float l1 = red[4] + red[5] + red[6] + red[7];
    spart[((size_t)(kv * 2)     * NSCH + ch) * 2]     = m0;
    spart[((size_t)(kv * 2)     * NSCH + ch) * 2 + 1] = l0;
    spart[((size_t)(kv * 2 + 1) * NSCH + ch) * 2]     = m1;
    spart[((size_t)(kv * 2 + 1) * NSCH + ch) * 2 + 1] = l1;
  }
}

// ---- K4: online-merge chunk partials -> global (M, L) per q-head. grid=HQ, 64 threads.
__global__ void k_red(const float* __restrict__ spart, float2* __restrict__ ML){
  int qh = blockIdx.x, lane = threadIdx.x;
  float M = -1e30f, L = 0.f;
  for (int j = lane; j < NSCH; j += 64){
    float mj = spart[((size_t)qh * NSCH + j) * 2];
    float lj = spart[((size_t)qh * NSCH + j) * 2 + 1];
    float nM = fmaxf(M, mj);
    L = L * __expf(M - nM) + lj * __expf(mj - nM);
    M = nM;
  }
  #pragma unroll
  for (int off = 32; off; off >>= 1){
    float Mo = __shfl_down(M, off, 64);
    float Lo = __shfl_down(L, off, 64);
    float nM = fmaxf(M, Mo);
    L = L * __expf(M - nM) + Lo * __expf(Mo - nM);
    M = nM;
  }
  if (lane == 0) ML[qh] = make_float2(M, L);
}

// ---- K5: partial O for BOTH GQA heads, c in [0, CC) only — branch-free.
// grid = HKV*NAV, 256 threads; 8 position-slices x 32 dim-threads (float4); unroll 4.
__global__ void k_av(const float* __restrict__ S,
                     const float2* __restrict__ ML,
                     const float* __restrict__ vcache,   // [HKV][CC][DH]
                     float* __restrict__ opart){         // [HQ][NAV][DH]
  __shared__ float part[2][8][DH];
  int kv = blockIdx.x >> 6, ch = blockIdx.x & 63;
  int c0 = ch << 8;
  int t = threadIdx.x;
  int s = t >> 5, d4 = (t & 31) * 4;
  float2 ml0 = ML[kv * 2], ml1 = ML[kv * 2 + 1];
  float M0 = ml0.x, Li0 = 1.f / ml0.y;
  float M1 = ml1.x, Li1 = 1.f / ml1.y;
  const float* S0 = S + (size_t)(kv * 2)     * SPAD;
  const float* S1 = S + (size_t)(kv * 2 + 1) * SPAD;
  const float* vbase = vcache + (size_t)kv * CC * DH + d4;
  float4 a0 = make_float4(0.f, 0.f, 0.f, 0.f);
  float4 a1 = make_float4(0.f, 0.f, 0.f, 0.f);
  #pragma unroll 4
  for (int i = 0; i < 32; ++i){
    int c = c0 + i * 8 + s;
    float p0 = __expf(S0[c] - M0);
    float p1 = __expf(S1[c] - M1);
    float4 v = *(const float4*)(vbase + (size_t)c * DH);
    a0.x += p0 * v.x; a0.y += p0 * v.y; a0.z += p0 * v.z; a0.w += p0 * v.w;
    a1.x += p1 * v.x; a1.y += p1 * v.y; a1.z += p1 * v.z; a1.w += p1 * v.w;
  }
  *(float4*)&part[0][s][d4] = a0;
  *(float4*)&part[1][s][d4] = a1;
  __syncthreads();
  {
    int hh = t >> 7, d = t & 127;
    float o = 0.f;
    #pragma unroll
    for (int ss = 0; ss < 8; ++ss) o += part[hh][ss][d];
    float Li = hh ? Li1 : Li0;
    int qh = kv * 2 + hh;
    opart[((size_t)qh * NAV + ch) * DH + d] = o * Li;
  }
}

// ---- K6: sum partials + new-token V term -> attn_in[qh*DH+d]
__global__ void k_osum(const float* __restrict__ opart,
                       const float* __restrict__ S,
                       const float2* __restrict__ ML,
                       const float* __restrict__ vnew,   // raw+3072: [HKV][DH]
                       float* __restrict__ attn_in){
  int qh = blockIdx.x, d = threadIdx.x;
  int kv = qh >> 1;
  float o = 0.f;
  for (int ch = 0; ch < NAV; ++ch)
    o += opart[((size_t)qh * NAV + ch) * DH + d];
  float2 ml = ML[qh];
  float pn = __expf(S[(size_t)qh * SPAD + CC] - ml.x) / ml.y;
  o += pn * vnew[kv * DH + d];
  attn_in[qh * DH + d] = o;
}

// ---- K7: o_proj GEMV. One wave per output element.
__global__ void k_oproj(const float* __restrict__ attn_in,
                        const float* __restrict__ Wo,
                        float* __restrict__ out){
  int wave = threadIdx.x >> 6, lane = threadIdx.x & 63;
  int e = blockIdx.x * 4 + wave;
  const float* W = Wo + (size_t)e * HID;
  float acc = 0.f;
  #pragma unroll
  for (int j = 0; j < 4; ++j){
    int base = (j * 64 + lane) * 8;
    float4 a0 = *(const float4*)(attn_in + base);
    float4 a1 = *(const float4*)(attn_in + base + 4);
    float4 b0 = *(const float4*)(W + base);
    float4 b1 = *(const float4*)(W + base + 4);
    acc += a0.x*b0.x + a0.y*b0.y + a0.z*b0.z + a0.w*b0.w
         + a1.x*b1.x + a1.y*b1.y + a1.z*b1.z + a1.w*b1.w;
  }
  #pragma unroll
  for (int off = 32; off; off >>= 1) acc += __shfl_down(acc, off, 64);
  if (lane == 0) out[e] = acc;
}

extern "C" void kernel_launch(void* const* d_in, const int* in_sizes, int n_in,
                              void* d_out, int out_size, void* d_ws, size_t ws_size,
                              hipStream_t stream){
  const float* x    = (const float*)d_in[0];
  const float* cosb = (const float*)d_in[1];
  const float* sinb = (const float*)d_in[2];
  const float* mask = (const float*)d_in[3];
  const float* kc   = (const float*)d_in[4];
  const float* vc   = (const float*)d_in[5];
  const float* Wq   = (const float*)d_in[6];
  const float* Wk   = (const float*)d_in[7];
  const float* Wv   = (const float*)d_in[8];
  const float* Wo   = (const float*)d_in[9];
  const float* qw   = (const float*)d_in[10];
  const float* kw   = (const float*)d_in[11];
  float* out = (float*)d_out;
  float* ws = (float*)d_ws;
  float* raw     = ws;                          // 4096
  float* qf      = ws + 4096;                   // 2048
  float* kf      = ws + 6144;                   // 1024
  float* S       = ws + 8192;                   // 16*16896 = 270336
  float* spart   = ws + 278528;                 // 16*65*2 = 2080
  float2* ML     = (float2*)(ws + 280608);      // 32 floats
  float* opart   = ws + 280640;                 // 16*64*128 = 131072
  float* attn_in = ws + 411712;                 // 2048

  k_qkv     <<<1024, 256, 0, stream>>>(x, Wq, Wk, Wv, raw);
  k_normrope<<<32,   128, 0, stream>>>(raw, cosb, sinb, qw, kw, qf, kf, out);
  k_scores  <<<HKV * NSCH, 256, 0, stream>>>(qf, kf, kc, mask, S, spart);
  k_red     <<<HQ, 64, 0, stream>>>(spart, ML);
  k_av      <<<HKV * NAV, 256, 0, stream>>>(S, ML, vc, opart);
  k_osum    <<<HQ, DH, 0, stream>>>(opart, S, ML, raw + 3072, attn_in);
  k_oproj   <<<512, 256, 0, stream>>>(attn_in, Wo, out);
}

// Round 7
// 216.628 us; speedup vs baseline: 3.0225x; 1.0055x over previous
//
#include <hip/hip_runtime.h>
#include <math.h>
#include <stddef.h>

#define HQ   16
#define HKV  8
#define DH   128
#define HID  2048
#define CC   16384
#define NCH  64             // flash chunks of 256: 64*256 = 16384 = CC
#define CHUNK 256

// d_out layout (FLOAT32, 4096 elements): [attn 2048][k_new 8*128][v 8*128]

// ---- K1: QKV projections. One wave per output element.
// raw[0..2047]=q (16x128), [2048..3071]=k (8x128), [3072..4095]=v (8x128)
__global__ void k_qkv(const float* __restrict__ x,
                      const float* __restrict__ Wq,
                      const float* __restrict__ Wk,
                      const float* __restrict__ Wv,
                      float* __restrict__ raw){
  int wave = threadIdx.x >> 6, lane = threadIdx.x & 63;
  int e = blockIdx.x * 4 + wave;
  const float* W;
  if (e < 2048)      W = Wq + (size_t)e * HID;
  else if (e < 3072) W = Wk + (size_t)(e - 2048) * HID;
  else               W = Wv + (size_t)(e - 3072) * HID;
  float acc = 0.f;
  #pragma unroll
  for (int j = 0; j < 4; ++j){
    int base = (j * 64 + lane) * 8;
    float4 a0 = *(const float4*)(x + base);
    float4 a1 = *(const float4*)(x + base + 4);
    float4 b0 = *(const float4*)(W + base);
    float4 b1 = *(const float4*)(W + base + 4);
    acc += a0.x*b0.x + a0.y*b0.y + a0.z*b0.z + a0.w*b0.w
         + a1.x*b1.x + a1.y*b1.y + a1.z*b1.z + a1.w*b1.w;
  }
  #pragma unroll
  for (int off = 32; off; off >>= 1) acc += __shfl_down(acc, off, 64);
  if (lane == 0) raw[e] = acc;
}

// ---- K2: RMSNorm + RoPE (q,k), v passthrough.
__global__ void k_normrope(const float* __restrict__ raw,
                           const float* __restrict__ cosb,
                           const float* __restrict__ sinb,
                           const float* __restrict__ qw,
                           const float* __restrict__ kw,
                           float* __restrict__ qf,
                           float* __restrict__ kf,
                           float* __restrict__ out){
  __shared__ float lds[DH];
  __shared__ float wsum[2];
  int b = blockIdx.x, t = threadIdx.x;
  if (b >= 24){  // v copy to d_out
    int h = b - 24;
    out[3072 + h * DH + t] = raw[3072 + h * DH + t];
    return;
  }
  bool isq = (b < 16);
  int h = isq ? b : b - 16;
  float val = isq ? raw[h * DH + t] : raw[2048 + h * DH + t];
  float ss = val * val;
  #pragma unroll
  for (int off = 32; off; off >>= 1) ss += __shfl_down(ss, off, 64);
  if ((t & 63) == 0) wsum[t >> 6] = ss;
  __syncthreads();
  float rms = sqrtf((wsum[0] + wsum[1]) / 128.f + 1e-6f);
  float w = isq ? qw[t] : kw[t];
  float normed = val / rms * w;
  lds[t] = normed;
  __syncthreads();
  float rot = (t < 64) ? -lds[t + 64] : lds[t - 64];
  float res = normed * cosb[t] + rot * sinb[t];
  if (isq) qf[h * DH + t] = res;
  else { kf[h * DH + t] = res; out[2048 + h * DH + t] = res; }
}

// ---- K3: fused flash-decode chunk kernel. grid = HKV*NCH, 256 threads.
// Computes scores (both GQA heads), chunk softmax, and partial O in one pass.
// No S materialization. Emits opart[qh][ch][128] and ml[qh][ch]={m,l}.
__global__ void k_flash(const float* __restrict__ qf,
                        const float* __restrict__ kcache,  // [HKV][DH][CC]
                        const float* __restrict__ vcache,  // [HKV][CC][DH]
                        const float* __restrict__ mask,    // [CC+1]
                        float* __restrict__ opart,         // [HQ][NCH][DH]
                        float2* __restrict__ ml){          // [HQ][NCH]
  __shared__ float q_s[2][DH];
  __shared__ float sc_part[4][2][CHUNK];   // d-group partial dots
  __shared__ float p_s[2][CHUNK];
  __shared__ float part[2][8][DH];
  __shared__ float red[8];
  int kv = blockIdx.x >> 6, ch = blockIdx.x & 63;
  int c0 = ch << 8;
  int t = threadIdx.x;
  q_s[t >> 7][t & 127] = qf[(kv * 2 + (t >> 7)) * DH + (t & 127)];
  __syncthreads();
  const float scale = 0.08838834764831845f;  // 128^-0.5

  // ---- Phase A: QK^T. Thread (dg, ln): 4 consecutive positions, 32 dims.
  {
    int dg = t >> 6, ln = t & 63;
    const float* kp = kcache + (size_t)kv * DH * CC + (size_t)(dg * 32) * CC + (c0 + ln * 4);
    float a00 = 0.f, a01 = 0.f, a02 = 0.f, a03 = 0.f;
    float a10 = 0.f, a11 = 0.f, a12 = 0.f, a13 = 0.f;
    #pragma unroll 8
    for (int dd = 0; dd < 32; ++dd){
      float4 kk = *(const float4*)(kp + (size_t)dd * CC);
      float q0 = q_s[0][dg * 32 + dd], q1 = q_s[1][dg * 32 + dd];
      a00 += q0 * kk.x; a01 += q0 * kk.y; a02 += q0 * kk.z; a03 += q0 * kk.w;
      a10 += q1 * kk.x; a11 += q1 * kk.y; a12 += q1 * kk.z; a13 += q1 * kk.w;
    }
    *(float4*)&sc_part[dg][0][ln * 4] = make_float4(a00, a01, a02, a03);
    *(float4*)&sc_part[dg][1][ln * 4] = make_float4(a10, a11, a12, a13);
  }
  __syncthreads();

  // ---- Phase B: combine partial dots, chunk softmax (m, l), p_s = exp(s-m).
  float s0, s1;
  {
    float mk = mask[c0 + t];
    s0 = (sc_part[0][0][t] + sc_part[1][0][t] + sc_part[2][0][t] + sc_part[3][0][t]) * scale + mk;
    s1 = (sc_part[0][1][t] + sc_part[1][1][t] + sc_part[2][1][t] + sc_part[3][1][t]) * scale + mk;
  }
  int wv = t >> 6, ln = t & 63;
  float lmax0 = s0, lmax1 = s1;
  #pragma unroll
  for (int off = 32; off; off >>= 1){
    lmax0 = fmaxf(lmax0, __shfl_down(lmax0, off, 64));
    lmax1 = fmaxf(lmax1, __shfl_down(lmax1, off, 64));
  }
  if (ln == 0){ red[wv] = lmax0; red[4 + wv] = lmax1; }
  __syncthreads();
  float m0 = fmaxf(fmaxf(red[0], red[1]), fmaxf(red[2], red[3]));
  float m1 = fmaxf(fmaxf(red[4], red[5]), fmaxf(red[6], red[7]));
  float p0 = __expf(s0 - m0);
  float p1 = __expf(s1 - m1);
  p_s[0][t] = p0;
  p_s[1][t] = p1;
  float ls0 = p0, ls1 = p1;
  #pragma unroll
  for (int off = 32; off; off >>= 1){
    ls0 += __shfl_down(ls0, off, 64);
    ls1 += __shfl_down(ls1, off, 64);
  }
  __syncthreads();
  if (ln == 0){ red[wv] = ls0; red[4 + wv] = ls1; }
  __syncthreads();
  if (t == 0){
    float l0 = red[0] + red[1] + red[2] + red[3];
    float l1 = red[4] + red[5] + red[6] + red[7];
    ml[(size_t)(kv * 2)     * NCH + ch] = make_float2(m0, l0);
    ml[(size_t)(kv * 2 + 1) * NCH + ch] = make_float2(m1, l1);
  }

  // ---- Phase C: partial O = sum_c p[c]*V[c][:]. 8 slices x 32 dim-threads.
  {
    int s = t >> 5, d4 = (t & 31) * 4;
    const float* vbase = vcache + (size_t)kv * CC * DH + d4;
    float4 a0 = make_float4(0.f, 0.f, 0.f, 0.f);
    float4 a1 = make_float4(0.f, 0.f, 0.f, 0.f);
    #pragma unroll 4
    for (int i = 0; i < 32; ++i){
      int off = i * 8 + s;
      float pp0 = p_s[0][off];
      float pp1 = p_s[1][off];
      float4 v = *(const float4*)(vbase + (size_t)(c0 + off) * DH);
      a0.x += pp0 * v.x; a0.y += pp0 * v.y; a0.z += pp0 * v.z; a0.w += pp0 * v.w;
      a1.x += pp1 * v.x; a1.y += pp1 * v.y; a1.z += pp1 * v.z; a1.w += pp1 * v.w;
    }
    *(float4*)&part[0][s][d4] = a0;
    *(float4*)&part[1][s][d4] = a1;
  }
  __syncthreads();
  {
    int hh = t >> 7, d = t & 127;
    float o = 0.f;
    #pragma unroll
    for (int ss = 0; ss < 8; ++ss) o += part[hh][ss][d];
    int qh = kv * 2 + hh;
    opart[((size_t)qh * NCH + ch) * DH + d] = o;
  }
}

// ---- K4: combine chunk partials + new-token term -> attn_in. grid=HQ, 128 threads.
__global__ void k_combine(const float* __restrict__ opart,
                          const float2* __restrict__ ml,
                          const float* __restrict__ qf,
                          const float* __restrict__ kf,
                          const float* __restrict__ vnew,   // raw+3072: [HKV][DH]
                          const float* __restrict__ mask,
                          float* __restrict__ attn_in){
  __shared__ float red[2];
  int qh = blockIdx.x, d = threadIdx.x;
  int kv = qh >> 1;
  // global max over chunk m's (each thread redundantly; 64 float2 = 512B, L2-hot)
  float M = -1e30f;
  #pragma unroll 8
  for (int ch = 0; ch < NCH; ++ch) M = fmaxf(M, ml[(size_t)qh * NCH + ch].x);
  // merge chunks
  float o = 0.f, L = 0.f;
  for (int ch = 0; ch < NCH; ++ch){
    float2 m = ml[(size_t)qh * NCH + ch];
    float w = __expf(m.x - M);
    L += m.y * w;
    o += w * opart[((size_t)qh * NCH + ch) * DH + d];
  }
  // new-token score: q . k_new
  float prod = qf[qh * DH + d] * kf[kv * DH + d];
  float sum = prod;
  #pragma unroll
  for (int off = 32; off; off >>= 1) sum += __shfl_down(sum, off, 64);
  if ((d & 63) == 0) red[d >> 6] = sum;
  __syncthreads();
  float s_new = (red[0] + red[1]) * 0.08838834764831845f + mask[CC];
  float pn = __expf(s_new - M);
  L += pn;
  o += pn * vnew[kv * DH + d];
  attn_in[qh * DH + d] = o / L;
}

// ---- K5: o_proj GEMV. One wave per output element.
__global__ void k_oproj(const float* __restrict__ attn_in,
                        const float* __restrict__ Wo,
                        float* __restrict__ out){
  int wave = threadIdx.x >> 6, lane = threadIdx.x & 63;
  int e = blockIdx.x * 4 + wave;
  const float* W = Wo + (size_t)e * HID;
  float acc = 0.f;
  #pragma unroll
  for (int j = 0; j < 4; ++j){
    int base = (j * 64 + lane) * 8;
    float4 a0 = *(const float4*)(attn_in + base);
    float4 a1 = *(const float4*)(attn_in + base + 4);
    float4 b0 = *(const float4*)(W + base);
    float4 b1 = *(const float4*)(W + base + 4);
    acc += a0.x*b0.x + a0.y*b0.y + a0.z*b0.z + a0.w*b0.w
         + a1.x*b1.x + a1.y*b1.y + a1.z*b1.z + a1.w*b1.w;
  }
  #pragma unroll
  for (int off = 32; off; off >>= 1) acc += __shfl_down(acc, off, 64);
  if (lane == 0) out[e] = acc;
}

extern "C" void kernel_launch(void* const* d_in, const int* in_sizes, int n_in,
                              void* d_out, int out_size, void* d_ws, size_t ws_size,
                              hipStream_t stream){
  const float* x    = (const float*)d_in[0];
  const float* cosb = (const float*)d_in[1];
  const float* sinb = (const float*)d_in[2];
  const float* mask = (const float*)d_in[3];
  const float* kc   = (const float*)d_in[4];
  const float* vc   = (const float*)d_in[5];
  const float* Wq   = (const float*)d_in[6];
  const float* Wk   = (const float*)d_in[7];
  const float* Wv   = (const float*)d_in[8];
  const float* Wo   = (const float*)d_in[9];
  const float* qw   = (const float*)d_in[10];
  const float* kw   = (const float*)d_in[11];
  float* out = (float*)d_out;
  float* ws = (float*)d_ws;
  float* raw     = ws;                          // 4096
  float* qf      = ws + 4096;                   // 2048
  float* kf      = ws + 6144;                   // 1024
  float* opart   = ws + 8192;                   // 16*64*128 = 131072
  float2* ML     = (float2*)(ws + 139264);      // 16*64 float2 = 2048 floats
  float* attn_in = ws + 141312;                 // 2048

  k_qkv     <<<1024, 256, 0, stream>>>(x, Wq, Wk, Wv, raw);
  k_normrope<<<32,   128, 0, stream>>>(raw, cosb, sinb, qw, kw, qf, kf, out);
  k_flash   <<<HKV * NCH, 256, 0, stream>>>(qf, kc, vc, mask, opart, ML);
  k_combine <<<HQ, 128, 0, stream>>>(opart, ML, qf, kf, raw + 3072, mask, attn_in);
  k_oproj   <<<512, 256, 0, stream>>>(attn_in, Wo, out);
}